// Round 7
// baseline (267.255 us; speedup 1.0000x reference)
//
#include <hip/hip_runtime.h>
#include <cstdint>

#define NN 16
#define W64 64
#define MT 64                    // M elements per workgroup
#define NSTAGE 17                // stage 0 = W1/f, stages 1..16 = graph nodes
#define IST 72                   // inpbuf row stride (halves): 144B -> 2-way max on b128 reads
#define WST 68                   // wbuf row stride: 136B = 8 mod 128 -> 2-way on B-frag reads

typedef _Float16 half8   __attribute__((ext_vector_type(8)));
typedef _Float16 half16  __attribute__((ext_vector_type(16)));
typedef float    floatx4 __attribute__((ext_vector_type(4)));

// ================== compile-time graph (np.random.RandomState(0)) ==================
// Validated on-device in prior session. Constexpr: masks fold, node tiles get
// live-range-compressed register slots.
struct GPlan {
    unsigned pred[NN];
    unsigned sinkmask;
    int slot[NSTAGE];            // slot[i]: node i (i<16); slot[16] = f
    int nslot;
};

constexpr unsigned mt_next(unsigned (&mt)[624], int &mti) {
    if (mti >= 624) {
        for (int i = 0; i < 624; ++i) {
            const unsigned y = (mt[i] & 0x80000000u) | (mt[(i + 1) % 624] & 0x7fffffffu);
            unsigned v = mt[(i + 397) % 624] ^ (y >> 1);
            if (y & 1u) v ^= 0x9908b0dfu;
            mt[i] = v;
        }
        mti = 0;
    }
    unsigned y = mt[mti++];
    y ^= y >> 11;
    y ^= (y << 7)  & 0x9d2c5680u;
    y ^= (y << 15) & 0xefc60000u;
    y ^= y >> 18;
    return y;
}
constexpr double mt_rnd(unsigned (&mt)[624], int &mti) {
    const unsigned a = mt_next(mt, mti) >> 5;
    const unsigned b = mt_next(mt, mti) >> 6;
    return (a * 67108864.0 + b) / 9007199254740992.0;
}
constexpr long mt_randint(unsigned (&mt)[624], int &mti, long n) {
    const unsigned long maxv = (unsigned long)n - 1;
    if (maxv == 0) return 0;
    unsigned long mask = maxv;
    mask |= mask >> 1;  mask |= mask >> 2;  mask |= mask >> 4;
    mask |= mask >> 8;  mask |= mask >> 16;
    unsigned long v = (unsigned long)mt_next(mt, mti) & mask;
    while (v > maxv) v = (unsigned long)mt_next(mt, mti) & mask;
    return (long)v;
}

constexpr GPlan build_plan() {
    GPlan P = {};
    unsigned mt[624] = {};
    mt[0] = 0u;
    for (int i = 1; i < 624; ++i)
        mt[i] = 1812433253u * (mt[i-1] ^ (mt[i-1] >> 30)) + (unsigned)i;
    int mti = 624;

    bool edge[NN][NN] = {};
    for (int i = 0; i < NN; ++i) {
        for (int d = 1; d <= 2; ++d) {
            int j = (i + d) & (NN - 1);
            if (mt_rnd(mt, mti) < 0.75) j = (int)mt_randint(mt, mti, NN);
            const int a = i < j ? i : j;
            const int b = i < j ? j : i;
            if (a != b) edge[a][b] = true;
        }
    }
    for (int a = 0; a < NN; ++a)
        for (int b = 0; b < NN; ++b)
            if (edge[a][b]) P.pred[b] |= 1u << a;
    for (int j = 1; j < NN; ++j) {
        if (!P.pred[j]) {
            const int a = (int)mt_randint(mt, mti, j);
            P.pred[j] |= 1u << a;
            edge[a][j] = true;
        }
    }
    unsigned succ[NN] = {};
    for (int a = 0; a < NN; ++a)
        for (int b = 0; b < NN; ++b)
            if (edge[a][b]) succ[a] |= 1u << b;
    for (int j = 0; j < NN; ++j)
        if (!succ[j]) P.sinkmask |= 1u << j;

    int lastuse[NSTAGE] = {};
    for (int v = 0; v < NSTAGE; ++v) lastuse[v] = -1;
    for (int j = 0; j < NN; ++j) {
        const unsigned pm = P.pred[j];
        if (pm == 0u) { if (j > lastuse[16]) lastuse[16] = j; }
        else for (int i = 0; i < NN; ++i)
            if (pm & (1u << i)) { if (j > lastuse[i]) lastuse[i] = j; }
    }
    for (int i = 0; i < NN; ++i)
        if (P.sinkmask & (1u << i)) lastuse[i] = 17;

    int defstage[NSTAGE] = {};
    for (int i = 0; i < NN; ++i) defstage[i] = i + 1;
    defstage[16] = 0;

    int nmax = 0;
    for (int s = 0; s <= 16; ++s) {
        const int w = (s == 0) ? 16 : (s - 1);
        bool busy[NSTAGE] = {};
        for (int v = 0; v < NSTAGE; ++v) {
            if (v == w) continue;
            if (defstage[v] < s && lastuse[v] >= s)
                busy[P.slot[v]] = true;
        }
        int k = 0;
        while (busy[k]) ++k;
        P.slot[w] = k;
        if (k + 1 > nmax) nmax = k + 1;
    }
    P.nslot = nmax;
    return P;
}

constexpr GPlan kPlan = build_plan();
constexpr int NSLOT = kPlan.nslot;

// ---------------- fast activations ----------------
__device__ __forceinline__ float act_tanh(float x)     { return 1.0f - 2.0f / (1.0f + __expf(2.0f * x)); }
__device__ __forceinline__ float act_elu(float x)      { return x > 0.0f ? x : __expf(x) - 1.0f; }
__device__ __forceinline__ float act_softplus(float x) { return fmaxf(x, 0.0f) + __logf(1.0f + __expf(-fabsf(x))); }
__device__ __forceinline__ float act_gauss(float x)    { return __expf(-0.5f * x * x); }

// compile-time activation dispatch (no runtime switch anywhere)
template<int A>
__device__ __forceinline__ float act_c(float x) {
    if constexpr (A == 0)      return act_tanh(x);
    else if constexpr (A == 1) return act_elu(x);
    else if constexpr (A == 2) return act_softplus(x);
    else if constexpr (A == 3) return __sinf(x);
    else                       return act_gauss(x);
}

// R6 post-mortem: v_cvt_pkrtz rounds TOWARD ZERO -> systematic bias, amplified
// by the correlated 64-wide dot each stage (gain ~Sigma|W| ~ 7x/stage, 16 deep)
// -> absmax 0.77. Plain (_Float16) casts are RNE (zero-mean, cancels): KEEP RNE.

__device__ __forceinline__ half8 cvt8(float4 a, float4 b) {
    half8 h;
    h[0]=(_Float16)a.x; h[1]=(_Float16)a.y; h[2]=(_Float16)a.z; h[3]=(_Float16)a.w;
    h[4]=(_Float16)b.x; h[5]=(_Float16)b.y; h[6]=(_Float16)b.z; h[7]=(_Float16)b.w;
    return h;
}

// ---------------- weight pre-conversion: fp32 -> fp16 into d_ws ----------------
// ws layout: stage 0 = W1[64][64], stage 1+j = gW[j][64][64]; [w'][k] row-major.
__global__ void convert_weights(const float* __restrict__ W1,
                                const float* __restrict__ gW,
                                _Float16* __restrict__ ws)
{
    const int i = blockIdx.x * 256 + threadIdx.x;
    if (i >= NSTAGE * 4096) return;
    const float v = (i < 4096) ? W1[i] : gW[i - 4096];
    ws[i] = (_Float16)v;
}

// ---------------- weight staging helpers (R0 pattern) ----------------
template<bool F16W, int S>
__device__ __forceinline__ void issue_wload(const _Float16* __restrict__ wsW,
    const float* __restrict__ W1, const float* __restrict__ gW, const int tid,
    uint4& h0, uint4& h1, float4& f0, float4& f1, float4& f2, float4& f3)
{
    if constexpr (F16W) {
        const uint4* src = (const uint4*)(wsW + S * 4096);
        h0 = src[tid];
        h1 = src[tid + 256];
    } else {
        const float* wbase;
        if constexpr (S == 0) wbase = W1; else wbase = gW + (S - 1) * 4096;
        const float4* src = (const float4*)wbase;
        f0 = src[2 * tid];       f1 = src[2 * tid + 1];
        f2 = src[2 * tid + 512]; f3 = src[2 * tid + 513];
    }
}

template<bool F16W>
__device__ __forceinline__ void write_wbuf(_Float16* __restrict__ wb,
    const int srow, const int sc8,
    uint4 h0, uint4 h1, float4 f0, float4 f1, float4 f2, float4 f3)
{
    if constexpr (F16W) {
        *(uint4*)&wb[srow * WST + sc8 * 8]        = h0;
        *(uint4*)&wb[(srow + 32) * WST + sc8 * 8] = h1;
    } else {
        *(half8*)&wb[srow * WST + sc8 * 8]        = cvt8(f0, f1);
        *(half8*)&wb[(srow + 32) * WST + sc8 * 8] = cvt8(f2, f3);
    }
}

// ---------------- one stage, R0-exact schedule + bit-exact grafts ----------------
// R2-R4 post-mortem: every restructure (barrier-free / 1-barrier dbuf / pinned
// prefetch) landed at 186-190us vs this structure's 113us. Body below is R0's
// loop body with RNE numerics preserved exactly; template<S> (R1-proof); only
// bit-exact deltas: (1) bias from LDS bbuf, (3) vectorized embed writes,
// (4) outW from LDS in the head.
template<bool F16W, int S>
__device__ __forceinline__ void do_stage(
    _Float16* __restrict__ inpbuf0, _Float16* __restrict__ inpbuf1,
    _Float16* __restrict__ wbuf, const float* __restrict__ bbuf,
    half16* hreg,
    const _Float16* __restrict__ wsW, const float* __restrict__ W1,
    const float* __restrict__ gW,
    const int tid, const int rowbase, const int c, const int q,
    const int srow, const int sc8)
{
    _Float16* rdbuf = (S & 1) ? inpbuf1 : inpbuf0;
    _Float16* wrbuf = (S & 1) ? inpbuf0 : inpbuf1;

    // prefetch next stage's W into regs (held across the stage; drained at
    // barrier1 with MFMA+epilogue as cover — the schedule that measured 113us)
    uint4  nh0 = {}, nh1 = {};
    float4 nf0 = {}, nf1 = {}, nf2 = {}, nf3 = {};
    if constexpr (S + 1 < NSTAGE)
        issue_wload<F16W, S + 1>(wsW, W1, gW, tid, nh0, nh1, nf0, nf1, nf2, nf3);

    // A fragments: A[m=lane&15][k=quad*8+j], rows rowbase..rowbase+15
    const half8 a0 = *(const half8*)&rdbuf[(rowbase + c) * IST +  0 + q * 8];
    const half8 a1 = *(const half8*)&rdbuf[(rowbase + c) * IST + 32 + q * 8];

    // B fragments from wbuf (stored [w'][k], i.e. B^T rows) + MFMA;
    // bias from LDS (delta 1): no vmcnt wait feeding the accumulator init
    floatx4 acc[4];
    #pragma unroll
    for (int t = 0; t < 4; ++t) {
        const half8 b0  = *(const half8*)&wbuf[(t * 16 + c) * WST +  0 + q * 8];
        const half8 b1f = *(const half8*)&wbuf[(t * 16 + c) * WST + 32 + q * 8];
        const float bs = bbuf[S * W64 + t * 16 + c];
        floatx4 z = {bs, bs, bs, bs};        // bias folded into accumulator init
        z = __builtin_amdgcn_mfma_f32_16x16x32_f16(a0, b0, z, 0, 0, 0);
        z = __builtin_amdgcn_mfma_f32_16x16x32_f16(a1, b1f, z, 0, 0, 0);
        acc[t] = z;
    }

    // epilogue: activation -> hreg slot (C-layout, packed), RNE casts (R0-exact)
    constexpr int an    = (S == 0) ? 3 : ((S - 1) % 5);        // stage0 act = sin
    constexpr int hslot = kPlan.slot[(S == 0) ? 16 : (S - 1)]; // constexpr-folds
    #pragma unroll
    for (int t = 0; t < 4; ++t)
        #pragma unroll
        for (int r = 0; r < 4; ++r)
            hreg[hslot][t * 4 + r] = (_Float16)act_c<an>(acc[t][r]);

    // build next stage's input (packed fp16 pred-sum, masks fold statically)
    if constexpr (S + 1 < NSTAGE) {
        constexpr unsigned pm = kPlan.pred[S];
        half16 sum;
        if constexpr (pm == 0u) {                 // source: input = f
            sum = hreg[kPlan.slot[16]];
        } else {
            #pragma unroll
            for (int v = 0; v < 16; ++v) sum[v] = (_Float16)0.0f;
            #pragma unroll
            for (int i = 0; i < NN; ++i)
                if (pm & (1u << i))               // dead branches removed
                    sum += hreg[kPlan.slot[i]];
        }
        // C-layout scatter: sum[t*4+r] -> row rowbase+q*4+r (16x b16, as R0)
        #pragma unroll
        for (int t = 0; t < 4; ++t)
            #pragma unroll
            for (int r = 0; r < 4; ++r)
                wrbuf[(rowbase + q * 4 + r) * IST + t * 16 + c] = sum[t * 4 + r];

        // barrier1: all waves' wbuf B-frag reads drained (lgkmcnt(0) precedes
        // s_barrier), safe to overwrite; prefetch vmcnt drains here too,
        // covered by the MFMA+epilogue above — exactly R0's schedule
        __syncthreads();
        write_wbuf<F16W>(wbuf, srow, sc8, nh0, nh1, nf0, nf1, nf2, nf3);
        // barrier2: new weights visible to all waves
        __syncthreads();
    }
}

// ---------------- main fused kernel (R0 structure + bit-exact grafts) ----------------
template<bool F16W>
__global__ __launch_bounds__(256, 3) void inr_mfma_kernel(
    const float* __restrict__ inputs, const float* __restrict__ latents,
    const float* __restrict__ Wl, const float* __restrict__ bl,
    const float* __restrict__ Wx, const float* __restrict__ Wy,
    const float* __restrict__ Wr, const float* __restrict__ W1,
    const float* __restrict__ b1, const float* __restrict__ gW,
    const float* __restrict__ gB, const float* __restrict__ outW,
    const float* __restrict__ outb, const float* __restrict__ scale,
    const _Float16* __restrict__ wsW,
    float* __restrict__ out, int Btot)
{
    __shared__ __align__(16) _Float16 inpbuf0[MT * IST];    //  9216 B
    __shared__ __align__(16) _Float16 inpbuf1[MT * IST];    //  9216 B
    __shared__ __align__(16) _Float16 wbuf[W64 * WST];      //  8704 B
    __shared__ __align__(16) float    bbuf[NSTAGE * W64];   //  4352 B
    __shared__ __align__(16) float    obuf[3 * W64];        //   768 B  (total 32256)

    const int tid  = threadIdx.x;
    const int lane = tid & 63;
    const int wv   = tid >> 6;            // wave id 0..3
    const int q    = lane >> 4;           // quad
    const int c    = lane & 15;           // col-in-tile
    const int rowbase = wv * 16;          // this wave's 16 M-rows within the tile
    const int m0   = blockIdx.x * MT;
    const int srow = tid >> 3;            // staging row 0..31
    const int sc8  = tid & 7;             // staging chunk-in-row 0..7

    // node state in MFMA C-layout, slot-compressed:
    // hreg[kPlan.slot[n]][t*4+r] = h_n[m = rowbase+q*4+r][w' = t*16+c]
    half16 hreg[NSLOT];

    // ---- prologue: issue W0 staging loads; stage biases + outW into LDS ----
    uint4  h0 = {}, h1 = {};
    float4 f0 = {}, f1 = {}, f2 = {}, f3 = {};
    issue_wload<F16W, 0>(wsW, W1, gW, tid, h0, h1, f0, f1, f2, f3);

    for (int i = tid; i < NSTAGE * W64; i += 256)
        bbuf[i] = (i < W64) ? b1[i] : gB[i - W64];
    if (tid < 3 * W64) obuf[tid] = outW[tid];

    // ---- embed: g0[m][k] -> inpbuf0 (thread t: m = t>>2, k = (t&3)*16..+15)
    {
        const int em = tid >> 2, ep = tid & 3;
        int mg = m0 + em; if (mg >= Btot) mg = Btot - 1;
        const float x = inputs[mg * 3 + 0];
        const float y = inputs[mg * 3 + 1];
        const float r = inputs[mg * 3 + 2];
        const float4 l0 = *(const float4*)(latents + mg * 8);
        const float4 l1 = *(const float4*)(latents + mg * 8 + 4);
        half8 hlo, hhi;
        #pragma unroll
        for (int i = 0; i < 16; ++i) {
            const int k = ep * 16 + i;
            const float4 a = *(const float4*)(Wl + k * 8);
            const float4 b = *(const float4*)(Wl + k * 8 + 4);
            float ld = bl[k];
            ld = fmaf(l0.x, a.x, ld); ld = fmaf(l0.y, a.y, ld);
            ld = fmaf(l0.z, a.z, ld); ld = fmaf(l0.w, a.w, ld);
            ld = fmaf(l1.x, b.x, ld); ld = fmaf(l1.y, b.y, ld);
            ld = fmaf(l1.z, b.z, ld); ld = fmaf(l1.w, b.w, ld);
            const float tk = act_tanh(x * Wx[k]) + act_softplus(y * Wy[k])
                           + act_elu(r * Wr[k]) + act_tanh(ld);
            const _Float16 hv = (_Float16)act_gauss(tk);
            if (i < 8) hlo[i] = hv; else hhi[i - 8] = hv;
        }
        *(half8*)&inpbuf0[em * IST + ep * 16]     = hlo;  // delta 3: 2x b128
        *(half8*)&inpbuf0[em * IST + ep * 16 + 8] = hhi;  // (rows wave-private)
    }

    // ---- land W0 (embed covered its latency), publish, run the chain ----
    write_wbuf<F16W>(wbuf, srow, sc8, h0, h1, f0, f1, f2, f3);
    __syncthreads();

    do_stage<F16W,  0>(inpbuf0, inpbuf1, wbuf, bbuf, hreg, wsW, W1, gW, tid, rowbase, c, q, srow, sc8);
    do_stage<F16W,  1>(inpbuf0, inpbuf1, wbuf, bbuf, hreg, wsW, W1, gW, tid, rowbase, c, q, srow, sc8);
    do_stage<F16W,  2>(inpbuf0, inpbuf1, wbuf, bbuf, hreg, wsW, W1, gW, tid, rowbase, c, q, srow, sc8);
    do_stage<F16W,  3>(inpbuf0, inpbuf1, wbuf, bbuf, hreg, wsW, W1, gW, tid, rowbase, c, q, srow, sc8);
    do_stage<F16W,  4>(inpbuf0, inpbuf1, wbuf, bbuf, hreg, wsW, W1, gW, tid, rowbase, c, q, srow, sc8);
    do_stage<F16W,  5>(inpbuf0, inpbuf1, wbuf, bbuf, hreg, wsW, W1, gW, tid, rowbase, c, q, srow, sc8);
    do_stage<F16W,  6>(inpbuf0, inpbuf1, wbuf, bbuf, hreg, wsW, W1, gW, tid, rowbase, c, q, srow, sc8);
    do_stage<F16W,  7>(inpbuf0, inpbuf1, wbuf, bbuf, hreg, wsW, W1, gW, tid, rowbase, c, q, srow, sc8);
    do_stage<F16W,  8>(inpbuf0, inpbuf1, wbuf, bbuf, hreg, wsW, W1, gW, tid, rowbase, c, q, srow, sc8);
    do_stage<F16W,  9>(inpbuf0, inpbuf1, wbuf, bbuf, hreg, wsW, W1, gW, tid, rowbase, c, q, srow, sc8);
    do_stage<F16W, 10>(inpbuf0, inpbuf1, wbuf, bbuf, hreg, wsW, W1, gW, tid, rowbase, c, q, srow, sc8);
    do_stage<F16W, 11>(inpbuf0, inpbuf1, wbuf, bbuf, hreg, wsW, W1, gW, tid, rowbase, c, q, srow, sc8);
    do_stage<F16W, 12>(inpbuf0, inpbuf1, wbuf, bbuf, hreg, wsW, W1, gW, tid, rowbase, c, q, srow, sc8);
    do_stage<F16W, 13>(inpbuf0, inpbuf1, wbuf, bbuf, hreg, wsW, W1, gW, tid, rowbase, c, q, srow, sc8);
    do_stage<F16W, 14>(inpbuf0, inpbuf1, wbuf, bbuf, hreg, wsW, W1, gW, tid, rowbase, c, q, srow, sc8);
    do_stage<F16W, 15>(inpbuf0, inpbuf1, wbuf, bbuf, hreg, wsW, W1, gW, tid, rowbase, c, q, srow, sc8);
    do_stage<F16W, 16>(inpbuf0, inpbuf1, wbuf, bbuf, hreg, wsW, W1, gW, tid, rowbase, c, q, srow, sc8);

    // ---- head: agg over sinks (packed fp16), LDS round trip, 3 dots, sigmoid ----
    // stage 16 read inpbuf0, so inpbuf1 is free scratch (wave-private rows)
    {
        half16 sum;
        #pragma unroll
        for (int v = 0; v < 16; ++v) sum[v] = (_Float16)0.0f;
        #pragma unroll
        for (int j = 0; j < NN; ++j) {
            if (kPlan.sinkmask & (1u << j)) {     // folds statically
                sum += hreg[kPlan.slot[j]];
            }
        }
        #pragma unroll
        for (int t = 0; t < 4; ++t)
            #pragma unroll
            for (int r = 0; r < 4; ++r)
                inpbuf1[(rowbase + q * 4 + r) * IST + t * 16 + c] = sum[t * 4 + r];
    }
    // inpbuf1 rows are wave-private; same-wave RAW ordered by lgkmcnt
    {
        const int em = tid >> 2, ep = tid & 3;
        float p0 = 0.f, p1 = 0.f, p2 = 0.f;
        #pragma unroll
        for (int h = 0; h < 2; ++h) {
            const half8 hv = *(const half8*)&inpbuf1[em * IST + ep * 16 + h * 8];
            #pragma unroll
            for (int i = 0; i < 8; ++i) {
                const float av = (float)hv[i];
                const int k = ep * 16 + h * 8 + i;
                p0 = fmaf(av, obuf[0 * W64 + k], p0);   // delta 4: outW from LDS
                p1 = fmaf(av, obuf[1 * W64 + k], p1);
                p2 = fmaf(av, obuf[2 * W64 + k], p2);
            }
        }
        p0 += __shfl_xor(p0, 1); p0 += __shfl_xor(p0, 2);
        p1 += __shfl_xor(p1, 1); p1 += __shfl_xor(p1, 2);
        p2 += __shfl_xor(p2, 1); p2 += __shfl_xor(p2, 2);
        const int mg = m0 + em;
        if (ep < 3 && mg < Btot) {
            const float pr = (ep == 0) ? p0 : ((ep == 1) ? p1 : p2);
            const float res = (pr + outb[ep]) * scale[0];
            out[mg * 3 + ep] = 1.0f / (1.0f + __expf(-res));
        }
    }
}

extern "C" void kernel_launch(void* const* d_in, const int* in_sizes, int n_in,
                              void* d_out, int out_size, void* d_ws, size_t ws_size,
                              hipStream_t stream)
{
    const float* inputs  = (const float*)d_in[0];
    const float* latents = (const float*)d_in[1];
    const float* Wl      = (const float*)d_in[2];
    const float* bl      = (const float*)d_in[3];
    const float* Wx      = (const float*)d_in[4];
    const float* Wy      = (const float*)d_in[5];
    const float* Wr      = (const float*)d_in[6];
    const float* W1      = (const float*)d_in[7];
    const float* b1      = (const float*)d_in[8];
    const float* gW      = (const float*)d_in[9];
    const float* gB      = (const float*)d_in[10];
    const float* outW    = (const float*)d_in[11];
    const float* outb    = (const float*)d_in[12];
    const float* scale   = (const float*)d_in[13];
    float* out = (float*)d_out;

    const int Btot = in_sizes[0] / 3;
    const int blocks = (Btot + MT - 1) / MT;
    const size_t wbytes = (size_t)NSTAGE * 4096 * sizeof(_Float16);  // 139264

    if (ws_size >= wbytes) {
        _Float16* wsW = (_Float16*)d_ws;
        convert_weights<<<(NSTAGE * 4096 + 255) / 256, 256, 0, stream>>>(W1, gW, wsW);
        inr_mfma_kernel<true><<<blocks, 256, 0, stream>>>(
            inputs, latents, Wl, bl, Wx, Wy, Wr, W1, b1, gW, gB, outW, outb, scale,
            wsW, out, Btot);
    } else {
        inr_mfma_kernel<false><<<blocks, 256, 0, stream>>>(
            inputs, latents, Wl, bl, Wx, Wy, Wr, W1, b1, gW, gB, outW, outb, scale,
            (const _Float16*)nullptr, out, Btot);
    }
}

// Round 8
// 263.779 us; speedup vs baseline: 1.0132x; 1.0132x over previous
//
#include <hip/hip_runtime.h>
#include <cstdint>

#define NN 16
#define W64 64
#define MT 64                    // M elements per workgroup
#define NSTAGE 17                // stage 0 = W1/f, stages 1..16 = graph nodes
#define IST 72                   // inpbuf row stride (halves): 144B -> 2-way max on b128 reads
#define WST 68                   // wbuf row stride: 136B = 8 mod 128 -> 2-way on B-frag reads

typedef _Float16 half8   __attribute__((ext_vector_type(8)));
typedef _Float16 half16  __attribute__((ext_vector_type(16)));
typedef float    floatx4 __attribute__((ext_vector_type(4)));
typedef unsigned int u32x4 __attribute__((ext_vector_type(4)));

// ================== compile-time graph (np.random.RandomState(0)) ==================
struct GPlan {
    unsigned pred[NN];
    unsigned sinkmask;
    int slot[NSTAGE];            // slot[i]: node i (i<16); slot[16] = f
    int nslot;
};

constexpr unsigned mt_next(unsigned (&mt)[624], int &mti) {
    if (mti >= 624) {
        for (int i = 0; i < 624; ++i) {
            const unsigned y = (mt[i] & 0x80000000u) | (mt[(i + 1) % 624] & 0x7fffffffu);
            unsigned v = mt[(i + 397) % 624] ^ (y >> 1);
            if (y & 1u) v ^= 0x9908b0dfu;
            mt[i] = v;
        }
        mti = 0;
    }
    unsigned y = mt[mti++];
    y ^= y >> 11;
    y ^= (y << 7)  & 0x9d2c5680u;
    y ^= (y << 15) & 0xefc60000u;
    y ^= y >> 18;
    return y;
}
constexpr double mt_rnd(unsigned (&mt)[624], int &mti) {
    const unsigned a = mt_next(mt, mti) >> 5;
    const unsigned b = mt_next(mt, mti) >> 6;
    return (a * 67108864.0 + b) / 9007199254740992.0;
}
constexpr long mt_randint(unsigned (&mt)[624], int &mti, long n) {
    const unsigned long maxv = (unsigned long)n - 1;
    if (maxv == 0) return 0;
    unsigned long mask = maxv;
    mask |= mask >> 1;  mask |= mask >> 2;  mask |= mask >> 4;
    mask |= mask >> 8;  mask |= mask >> 16;
    unsigned long v = (unsigned long)mt_next(mt, mti) & mask;
    while (v > maxv) v = (unsigned long)mt_next(mt, mti) & mask;
    return (long)v;
}

constexpr GPlan build_plan() {
    GPlan P = {};
    unsigned mt[624] = {};
    mt[0] = 0u;
    for (int i = 1; i < 624; ++i)
        mt[i] = 1812433253u * (mt[i-1] ^ (mt[i-1] >> 30)) + (unsigned)i;
    int mti = 624;

    bool edge[NN][NN] = {};
    for (int i = 0; i < NN; ++i) {
        for (int d = 1; d <= 2; ++d) {
            int j = (i + d) & (NN - 1);
            if (mt_rnd(mt, mti) < 0.75) j = (int)mt_randint(mt, mti, NN);
            const int a = i < j ? i : j;
            const int b = i < j ? j : i;
            if (a != b) edge[a][b] = true;
        }
    }
    for (int a = 0; a < NN; ++a)
        for (int b = 0; b < NN; ++b)
            if (edge[a][b]) P.pred[b] |= 1u << a;
    for (int j = 1; j < NN; ++j) {
        if (!P.pred[j]) {
            const int a = (int)mt_randint(mt, mti, j);
            P.pred[j] |= 1u << a;
            edge[a][j] = true;
        }
    }
    unsigned succ[NN] = {};
    for (int a = 0; a < NN; ++a)
        for (int b = 0; b < NN; ++b)
            if (edge[a][b]) succ[a] |= 1u << b;
    for (int j = 0; j < NN; ++j)
        if (!succ[j]) P.sinkmask |= 1u << j;

    int lastuse[NSTAGE] = {};
    for (int v = 0; v < NSTAGE; ++v) lastuse[v] = -1;
    for (int j = 0; j < NN; ++j) {
        const unsigned pm = P.pred[j];
        if (pm == 0u) { if (j > lastuse[16]) lastuse[16] = j; }
        else for (int i = 0; i < NN; ++i)
            if (pm & (1u << i)) { if (j > lastuse[i]) lastuse[i] = j; }
    }
    for (int i = 0; i < NN; ++i)
        if (P.sinkmask & (1u << i)) lastuse[i] = 17;

    int defstage[NSTAGE] = {};
    for (int i = 0; i < NN; ++i) defstage[i] = i + 1;
    defstage[16] = 0;

    int nmax = 0;
    for (int s = 0; s <= 16; ++s) {
        const int w = (s == 0) ? 16 : (s - 1);
        bool busy[NSTAGE] = {};
        for (int v = 0; v < NSTAGE; ++v) {
            if (v == w) continue;
            if (defstage[v] < s && lastuse[v] >= s)
                busy[P.slot[v]] = true;
        }
        int k = 0;
        while (busy[k]) ++k;
        P.slot[w] = k;
        if (k + 1 > nmax) nmax = k + 1;
    }
    P.nslot = nmax;
    return P;
}

constexpr GPlan kPlan = build_plan();
constexpr int NSLOT = kPlan.nslot;

// ---------------- fast activations ----------------
__device__ __forceinline__ float act_tanh(float x)     { return 1.0f - 2.0f / (1.0f + __expf(2.0f * x)); }
__device__ __forceinline__ float act_elu(float x)      { return x > 0.0f ? x : __expf(x) - 1.0f; }
__device__ __forceinline__ float act_softplus(float x) { return fmaxf(x, 0.0f) + __logf(1.0f + __expf(-fabsf(x))); }
__device__ __forceinline__ float act_gauss(float x)    { return __expf(-0.5f * x * x); }

// compile-time activation dispatch; RNE casts everywhere (R6: cvt_pkrtz's RTZ
// bias is amplified ~7x/stage by the 64-wide dot -> absmax 0.77; keep RNE).
template<int A>
__device__ __forceinline__ float act_c(float x) {
    if constexpr (A == 0)      return act_tanh(x);
    else if constexpr (A == 1) return act_elu(x);
    else if constexpr (A == 2) return act_softplus(x);
    else if constexpr (A == 3) return __sinf(x);
    else                       return act_gauss(x);
}

__device__ __forceinline__ half8 cvt8(float4 a, float4 b) {
    half8 h;
    h[0]=(_Float16)a.x; h[1]=(_Float16)a.y; h[2]=(_Float16)a.z; h[3]=(_Float16)a.w;
    h[4]=(_Float16)b.x; h[5]=(_Float16)b.y; h[6]=(_Float16)b.z; h[7]=(_Float16)b.w;
    return h;
}

// ---------------- weight pre-conversion: fp32 -> fp16 into d_ws ----------------
// ws layout: stage 0 = W1[64][64], stage 1+j = gW[j][64][64]; [w'][k] row-major.
__global__ void convert_weights(const float* __restrict__ W1,
                                const float* __restrict__ gW,
                                _Float16* __restrict__ ws)
{
    const int i = blockIdx.x * 256 + threadIdx.x;
    if (i >= NSTAGE * 4096) return;
    const float v = (i < 4096) ? W1[i] : gW[i - 4096];
    ws[i] = (_Float16)v;
}

// ---------------- weight staging ----------------
// R7 post-mortem: the ledger across R0/R2/R3/R4/R7 shows VGPR tracks perf
// exactly (80 -> 113us; 64-72 -> 186-198us): the ONLY fast schedule is
// "prefetch issued at stage top, HELD in VGPRs, drained at barrier1 with
// MFMA+epilogue as cover". The compiler sinks plain loads to their use at
// write_wbuf (zero cover) whenever it feels like it. Volatile inline-asm
// loads CANNOT be sunk -> the R0 schedule is now guaranteed, not lucky.
template<int S>
__device__ __forceinline__ void issue_wload_asm(const _Float16* __restrict__ wsW,
    const int tid, u32x4& h0, u32x4& h1)
{
    const u32x4* src = (const u32x4*)(wsW + S * 4096);
    asm volatile("global_load_dwordx4 %0, %1, off"
                 : "=&v"(h0) : "v"(src + tid) : "memory");
    asm volatile("global_load_dwordx4 %0, %1, off"
                 : "=&v"(h1) : "v"(src + tid + 256) : "memory");
}

template<int S>
__device__ __forceinline__ void issue_wload_f32(
    const float* __restrict__ W1, const float* __restrict__ gW, const int tid,
    float4& f0, float4& f1, float4& f2, float4& f3)
{
    const float* wbase;
    if constexpr (S == 0) wbase = W1; else wbase = gW + (S - 1) * 4096;
    const float4* src = (const float4*)wbase;
    f0 = src[2 * tid];       f1 = src[2 * tid + 1];
    f2 = src[2 * tid + 512]; f3 = src[2 * tid + 513];
}

// NOTE: the compiler does NOT track vmcnt for asm loads, so before consuming
// h0/h1 we must drain explicitly — the auto s_waitcnt before s_barrier only
// covers loads the compiler knows about. Mandatory for correctness.
__device__ __forceinline__ void drain_vmcnt() {
    asm volatile("s_waitcnt vmcnt(0)" ::: "memory");
}

template<bool F16W>
__device__ __forceinline__ void write_wbuf(_Float16* __restrict__ wb,
    const int srow, const int sc8,
    u32x4 h0, u32x4 h1, float4 f0, float4 f1, float4 f2, float4 f3)
{
    if constexpr (F16W) {
        *(u32x4*)&wb[srow * WST + sc8 * 8]        = h0;
        *(u32x4*)&wb[(srow + 32) * WST + sc8 * 8] = h1;
    } else {
        *(half8*)&wb[srow * WST + sc8 * 8]        = cvt8(f0, f1);
        *(half8*)&wb[(srow + 32) * WST + sc8 * 8] = cvt8(f2, f3);
    }
}

// ---------------- one stage: R0 schedule with the prefetch PINNED ----------------
template<bool F16W, int S>
__device__ __forceinline__ void do_stage(
    _Float16* __restrict__ inpbuf0, _Float16* __restrict__ inpbuf1,
    _Float16* __restrict__ wbuf, const float* __restrict__ bbuf,
    half16* hreg,
    const _Float16* __restrict__ wsW, const float* __restrict__ W1,
    const float* __restrict__ gW,
    const int tid, const int rowbase, const int c, const int q,
    const int srow, const int sc8)
{
    _Float16* rdbuf = (S & 1) ? inpbuf1 : inpbuf0;
    _Float16* wrbuf = (S & 1) ? inpbuf0 : inpbuf1;

    // prefetch next stage's W at stage TOP — volatile asm, cannot sink;
    // cover = MFMA + epilogue; drain at barrier1 (R0's measured schedule)
    u32x4  nh0 = {}, nh1 = {};
    float4 nf0 = {}, nf1 = {}, nf2 = {}, nf3 = {};
    if constexpr (S + 1 < NSTAGE) {
        if constexpr (F16W) issue_wload_asm<S + 1>(wsW, tid, nh0, nh1);
        else                issue_wload_f32<S + 1>(W1, gW, tid, nf0, nf1, nf2, nf3);
    }

    // A fragments: A[m=lane&15][k=quad*8+j], rows rowbase..rowbase+15
    const half8 a0 = *(const half8*)&rdbuf[(rowbase + c) * IST +  0 + q * 8];
    const half8 a1 = *(const half8*)&rdbuf[(rowbase + c) * IST + 32 + q * 8];

    // B fragments from wbuf (stored [w'][k], i.e. B^T rows) + MFMA;
    // bias from LDS bbuf — no vmcnt ops inside the stage body at all now
    floatx4 acc[4];
    #pragma unroll
    for (int t = 0; t < 4; ++t) {
        const half8 b0  = *(const half8*)&wbuf[(t * 16 + c) * WST +  0 + q * 8];
        const half8 b1f = *(const half8*)&wbuf[(t * 16 + c) * WST + 32 + q * 8];
        const float bs = bbuf[S * W64 + t * 16 + c];
        floatx4 z = {bs, bs, bs, bs};        // bias folded into accumulator init
        z = __builtin_amdgcn_mfma_f32_16x16x32_f16(a0, b0, z, 0, 0, 0);
        z = __builtin_amdgcn_mfma_f32_16x16x32_f16(a1, b1f, z, 0, 0, 0);
        acc[t] = z;
    }

    // epilogue: activation -> hreg slot (C-layout, packed), RNE casts (R0-exact)
    constexpr int an    = (S == 0) ? 3 : ((S - 1) % 5);        // stage0 act = sin
    constexpr int hslot = kPlan.slot[(S == 0) ? 16 : (S - 1)]; // constexpr-folds
    #pragma unroll
    for (int t = 0; t < 4; ++t)
        #pragma unroll
        for (int r = 0; r < 4; ++r)
            hreg[hslot][t * 4 + r] = (_Float16)act_c<an>(acc[t][r]);

    // build next stage's input (packed fp16 pred-sum, masks fold statically)
    if constexpr (S + 1 < NSTAGE) {
        constexpr unsigned pm = kPlan.pred[S];
        half16 sum;
        if constexpr (pm == 0u) {                 // source: input = f
            sum = hreg[kPlan.slot[16]];
        } else {
            #pragma unroll
            for (int v = 0; v < 16; ++v) sum[v] = (_Float16)0.0f;
            #pragma unroll
            for (int i = 0; i < NN; ++i)
                if (pm & (1u << i))               // dead branches removed
                    sum += hreg[kPlan.slot[i]];
        }
        // C-layout scatter: sum[t*4+r] -> row rowbase+q*4+r (16x b16, as R0)
        #pragma unroll
        for (int t = 0; t < 4; ++t)
            #pragma unroll
            for (int r = 0; r < 4; ++r)
                wrbuf[(rowbase + q * 4 + r) * IST + t * 16 + c] = sum[t * 4 + r];

        // barrier1: all waves' wbuf B-frag reads drained; prefetch vmcnt
        // drains here too, covered by the MFMA+epilogue above
        __syncthreads();
        if constexpr (F16W) drain_vmcnt();   // asm loads invisible to compiler
        write_wbuf<F16W>(wbuf, srow, sc8, nh0, nh1, nf0, nf1, nf2, nf3);
        // barrier2: new weights visible to all waves
        __syncthreads();
    }
}

// ---------------- main fused kernel ----------------
template<bool F16W>
__global__ __launch_bounds__(256, 3) void inr_mfma_kernel(
    const float* __restrict__ inputs, const float* __restrict__ latents,
    const float* __restrict__ Wl, const float* __restrict__ bl,
    const float* __restrict__ Wx, const float* __restrict__ Wy,
    const float* __restrict__ Wr, const float* __restrict__ W1,
    const float* __restrict__ b1, const float* __restrict__ gW,
    const float* __restrict__ gB, const float* __restrict__ outW,
    const float* __restrict__ outb, const float* __restrict__ scale,
    const _Float16* __restrict__ wsW,
    float* __restrict__ out, int Btot)
{
    __shared__ __align__(16) _Float16 inpbuf0[MT * IST];    //  9216 B
    __shared__ __align__(16) _Float16 inpbuf1[MT * IST];    //  9216 B
    __shared__ __align__(16) _Float16 wbuf[W64 * WST];      //  8704 B
    __shared__ __align__(16) float    bbuf[NSTAGE * W64];   //  4352 B
    __shared__ __align__(16) float    obuf[3 * W64];        //   768 B  (total 32256)

    const int tid  = threadIdx.x;
    const int lane = tid & 63;
    const int wv   = tid >> 6;            // wave id 0..3
    const int q    = lane >> 4;           // quad
    const int c    = lane & 15;           // col-in-tile
    const int rowbase = wv * 16;          // this wave's 16 M-rows within the tile
    const int m0   = blockIdx.x * MT;
    const int srow = tid >> 3;            // staging row 0..31
    const int sc8  = tid & 7;             // staging chunk-in-row 0..7

    // node state in MFMA C-layout, slot-compressed:
    // hreg[kPlan.slot[n]][t*4+r] = h_n[m = rowbase+q*4+r][w' = t*16+c]
    half16 hreg[NSLOT];

    // ---- prologue: issue W0 staging loads (pinned); stage biases + outW ----
    u32x4  h0 = {}, h1 = {};
    float4 f0 = {}, f1 = {}, f2 = {}, f3 = {};
    if constexpr (F16W) issue_wload_asm<0>(wsW, tid, h0, h1);
    else                issue_wload_f32<0>(W1, gW, tid, f0, f1, f2, f3);

    for (int i = tid; i < NSTAGE * W64; i += 256)
        bbuf[i] = (i < W64) ? b1[i] : gB[i - W64];
    if (tid < 3 * W64) obuf[tid] = outW[tid];

    // ---- embed: g0[m][k] -> inpbuf0 (thread t: m = t>>2, k = (t&3)*16..+15)
    {
        const int em = tid >> 2, ep = tid & 3;
        int mg = m0 + em; if (mg >= Btot) mg = Btot - 1;
        const float x = inputs[mg * 3 + 0];
        const float y = inputs[mg * 3 + 1];
        const float r = inputs[mg * 3 + 2];
        const float4 l0 = *(const float4*)(latents + mg * 8);
        const float4 l1 = *(const float4*)(latents + mg * 8 + 4);
        half8 hlo, hhi;
        #pragma unroll
        for (int i = 0; i < 16; ++i) {
            const int k = ep * 16 + i;
            const float4 a = *(const float4*)(Wl + k * 8);
            const float4 b = *(const float4*)(Wl + k * 8 + 4);
            float ld = bl[k];
            ld = fmaf(l0.x, a.x, ld); ld = fmaf(l0.y, a.y, ld);
            ld = fmaf(l0.z, a.z, ld); ld = fmaf(l0.w, a.w, ld);
            ld = fmaf(l1.x, b.x, ld); ld = fmaf(l1.y, b.y, ld);
            ld = fmaf(l1.z, b.z, ld); ld = fmaf(l1.w, b.w, ld);
            const float tk = act_tanh(x * Wx[k]) + act_softplus(y * Wy[k])
                           + act_elu(r * Wr[k]) + act_tanh(ld);
            const _Float16 hv = (_Float16)act_gauss(tk);
            if (i < 8) hlo[i] = hv; else hhi[i - 8] = hv;
        }
        *(half8*)&inpbuf0[em * IST + ep * 16]     = hlo;  // 2x ds_write_b128
        *(half8*)&inpbuf0[em * IST + ep * 16 + 8] = hhi;  // (rows wave-private)
    }

    // ---- land W0 (embed covered its latency), publish, run the chain ----
    if constexpr (F16W) drain_vmcnt();   // asm loads invisible to compiler
    write_wbuf<F16W>(wbuf, srow, sc8, h0, h1, f0, f1, f2, f3);
    __syncthreads();

    do_stage<F16W,  0>(inpbuf0, inpbuf1, wbuf, bbuf, hreg, wsW, W1, gW, tid, rowbase, c, q, srow, sc8);
    do_stage<F16W,  1>(inpbuf0, inpbuf1, wbuf, bbuf, hreg, wsW, W1, gW, tid, rowbase, c, q, srow, sc8);
    do_stage<F16W,  2>(inpbuf0, inpbuf1, wbuf, bbuf, hreg, wsW, W1, gW, tid, rowbase, c, q, srow, sc8);
    do_stage<F16W,  3>(inpbuf0, inpbuf1, wbuf, bbuf, hreg, wsW, W1, gW, tid, rowbase, c, q, srow, sc8);
    do_stage<F16W,  4>(inpbuf0, inpbuf1, wbuf, bbuf, hreg, wsW, W1, gW, tid, rowbase, c, q, srow, sc8);
    do_stage<F16W,  5>(inpbuf0, inpbuf1, wbuf, bbuf, hreg, wsW, W1, gW, tid, rowbase, c, q, srow, sc8);
    do_stage<F16W,  6>(inpbuf0, inpbuf1, wbuf, bbuf, hreg, wsW, W1, gW, tid, rowbase, c, q, srow, sc8);
    do_stage<F16W,  7>(inpbuf0, inpbuf1, wbuf, bbuf, hreg, wsW, W1, gW, tid, rowbase, c, q, srow, sc8);
    do_stage<F16W,  8>(inpbuf0, inpbuf1, wbuf, bbuf, hreg, wsW, W1, gW, tid, rowbase, c, q, srow, sc8);
    do_stage<F16W,  9>(inpbuf0, inpbuf1, wbuf, bbuf, hreg, wsW, W1, gW, tid, rowbase, c, q, srow, sc8);
    do_stage<F16W, 10>(inpbuf0, inpbuf1, wbuf, bbuf, hreg, wsW, W1, gW, tid, rowbase, c, q, srow, sc8);
    do_stage<F16W, 11>(inpbuf0, inpbuf1, wbuf, bbuf, hreg, wsW, W1, gW, tid, rowbase, c, q, srow, sc8);
    do_stage<F16W, 12>(inpbuf0, inpbuf1, wbuf, bbuf, hreg, wsW, W1, gW, tid, rowbase, c, q, srow, sc8);
    do_stage<F16W, 13>(inpbuf0, inpbuf1, wbuf, bbuf, hreg, wsW, W1, gW, tid, rowbase, c, q, srow, sc8);
    do_stage<F16W, 14>(inpbuf0, inpbuf1, wbuf, bbuf, hreg, wsW, W1, gW, tid, rowbase, c, q, srow, sc8);
    do_stage<F16W, 15>(inpbuf0, inpbuf1, wbuf, bbuf, hreg, wsW, W1, gW, tid, rowbase, c, q, srow, sc8);
    do_stage<F16W, 16>(inpbuf0, inpbuf1, wbuf, bbuf, hreg, wsW, W1, gW, tid, rowbase, c, q, srow, sc8);

    // ---- head: agg over sinks (packed fp16), LDS round trip, 3 dots, sigmoid ----
    // stage 16 read inpbuf0, so inpbuf1 is free scratch (wave-private rows)
    {
        half16 sum;
        #pragma unroll
        for (int v = 0; v < 16; ++v) sum[v] = (_Float16)0.0f;
        #pragma unroll
        for (int j = 0; j < NN; ++j) {
            if (kPlan.sinkmask & (1u << j)) {     // folds statically
                sum += hreg[kPlan.slot[j]];
            }
        }
        #pragma unroll
        for (int t = 0; t < 4; ++t)
            #pragma unroll
            for (int r = 0; r < 4; ++r)
                inpbuf1[(rowbase + q * 4 + r) * IST + t * 16 + c] = sum[t * 4 + r];
    }
    // inpbuf1 rows are wave-private; same-wave RAW ordered by lgkmcnt
    {
        const int em = tid >> 2, ep = tid & 3;
        float p0 = 0.f, p1 = 0.f, p2 = 0.f;
        #pragma unroll
        for (int h = 0; h < 2; ++h) {
            const half8 hv = *(const half8*)&inpbuf1[em * IST + ep * 16 + h * 8];
            #pragma unroll
            for (int i = 0; i < 8; ++i) {
                const float av = (float)hv[i];
                const int k = ep * 16 + h * 8 + i;
                p0 = fmaf(av, obuf[0 * W64 + k], p0);
                p1 = fmaf(av, obuf[1 * W64 + k], p1);
                p2 = fmaf(av, obuf[2 * W64 + k], p2);
            }
        }
        p0 += __shfl_xor(p0, 1); p0 += __shfl_xor(p0, 2);
        p1 += __shfl_xor(p1, 1); p1 += __shfl_xor(p1, 2);
        p2 += __shfl_xor(p2, 1); p2 += __shfl_xor(p2, 2);
        const int mg = m0 + em;
        if (ep < 3 && mg < Btot) {
            const float pr = (ep == 0) ? p0 : ((ep == 1) ? p1 : p2);
            const float res = (pr + outb[ep]) * scale[0];
            out[mg * 3 + ep] = 1.0f / (1.0f + __expf(-res));
        }
    }
}

extern "C" void kernel_launch(void* const* d_in, const int* in_sizes, int n_in,
                              void* d_out, int out_size, void* d_ws, size_t ws_size,
                              hipStream_t stream)
{
    const float* inputs  = (const float*)d_in[0];
    const float* latents = (const float*)d_in[1];
    const float* Wl      = (const float*)d_in[2];
    const float* bl      = (const float*)d_in[3];
    const float* Wx      = (const float*)d_in[4];
    const float* Wy      = (const float*)d_in[5];
    const float* Wr      = (const float*)d_in[6];
    const float* W1      = (const float*)d_in[7];
    const float* b1      = (const float*)d_in[8];
    const float* gW      = (const float*)d_in[9];
    const float* gB      = (const float*)d_in[10];
    const float* outW    = (const float*)d_in[11];
    const float* outb    = (const float*)d_in[12];
    const float* scale   = (const float*)d_in[13];
    float* out = (float*)d_out;

    const int Btot = in_sizes[0] / 3;
    const int blocks = (Btot + MT - 1) / MT;
    const size_t wbytes = (size_t)NSTAGE * 4096 * sizeof(_Float16);  // 139264

    if (ws_size >= wbytes) {
        _Float16* wsW = (_Float16*)d_ws;
        convert_weights<<<(NSTAGE * 4096 + 255) / 256, 256, 0, stream>>>(W1, gW, wsW);
        inr_mfma_kernel<true><<<blocks, 256, 0, stream>>>(
            inputs, latents, Wl, bl, Wx, Wy, Wr, W1, b1, gW, gB, outW, outb, scale,
            wsW, out, Btot);
    } else {
        inr_mfma_kernel<false><<<blocks, 256, 0, stream>>>(
            inputs, latents, Wl, bl, Wx, Wy, Wr, W1, b1, gW, gB, outW, outb, scale,
            (const _Float16*)nullptr, out, Btot);
    }
}